// Round 15
// baseline (181.929 us; speedup 1.0000x reference)
//
#include <hip/hip_runtime.h>

// GiGCNConv: out[d] = b + (1/deg[d]) * ( h[d] + sum_{e:(s->d)} ew[e]*h[s] )
//   h = x @ W,  deg[d] = 1 + sum_{e:dst==d} ew[e]
//
// Round-15 = round-14 with partgemm at 512 threads / 8 edges per thread:
//   round-14 measured partgemm Occupancy 37.7% (782 blocks x 4 waves under-
//   fills the machine). Same BATCHA (4096), same bin run lengths, same
//   traffic -- just 2x waves per block (6256 waves ~ 76%) and half the
//   staged registers. Fused gemm body does 64 rows/block (union LDS 32KB).
//
// Inputs: x f32[N*64], edge_index i32[2*E], edge_weight f32[E],
//         W f32[64*64], b f32[64].  Output f32[N*64].

#define D 64
#define BSH 9                // 512 nodes per bucket
#define NPB 512
#define MAXB1 256            // N <= 131072
#define BATCHA 4096
#define C1S 32
#define WSCALE 8192.0f
#define WINV (1.0f / 8192.0f)

static __device__ __forceinline__ unsigned short f2bf(float f) {
    unsigned u = __float_as_uint(f);
    u += 0x7FFFu + ((u >> 16) & 1u);
    return (unsigned short)(u >> 16);
}
static __device__ __forceinline__ float bflo(unsigned u) {
    return __uint_as_float(u << 16);
}
static __device__ __forceinline__ float bfhi(unsigned u) {
    return __uint_as_float(u & 0xFFFF0000u);
}

// ---------------- 1. bucket histogram ----------------

__global__ __launch_bounds__(256) void hist_kernel(const int* __restrict__ dst,
                                                   int* __restrict__ hist, int E, int B1) {
    __shared__ int lh[MAXB1];
    int tid = threadIdx.x;
    if (tid < MAXB1) lh[tid] = 0;
    __syncthreads();
    int t = blockIdx.x * 256 + tid;
    int stride = gridDim.x * 256;
    if ((E & 3) == 0 && (((size_t)dst & 15) == 0)) {
        const int4* d4 = (const int4*)dst;
        int n4 = E >> 2;
        for (int e = t; e < n4; e += stride) {
            int4 v = d4[e];
            atomicAdd(&lh[v.x >> BSH], 1);
            atomicAdd(&lh[v.y >> BSH], 1);
            atomicAdd(&lh[v.z >> BSH], 1);
            atomicAdd(&lh[v.w >> BSH], 1);
        }
    } else {
        for (int e = t; e < E; e += stride) {
            int d = __builtin_nontemporal_load(dst + e);
            atomicAdd(&lh[d >> BSH], 1);
        }
    }
    __syncthreads();
    if (tid < B1) {
        int v = lh[tid];
        if (v) atomicAdd(&hist[tid], v);
    }
}

// ---------------- 2. scan (single block, <=256 bins) ----------------

__global__ __launch_bounds__(256) void scan_kernel(const int* __restrict__ hist,
                                                   int* __restrict__ off1,
                                                   int* __restrict__ cur1, int B1, int E) {
    __shared__ int s[256];
    int tid = threadIdx.x;
    int v = (tid < B1) ? hist[tid] : 0;
    s[tid] = v;
    __syncthreads();
    for (int o = 1; o < 256; o <<= 1) {
        int t = (tid >= o) ? s[tid - o] : 0;
        __syncthreads();
        s[tid] += t;
        __syncthreads();
    }
    if (tid < B1) {
        int ex = s[tid] - v;
        off1[tid] = ex;
        cur1[tid * C1S] = ex;
    }
    if (tid == 0) off1[B1] = E;
}

// ---------------- 3. FUSED: partA (blocks < gA) + gemmW (blocks >= gA) ----------------
// 512 threads. pair1 = { src | (dst & 511) << 17 , ew }   (src <= 17 bits)

__global__ __launch_bounds__(512) void partgemm_kernel(const int* __restrict__ src,
                                                       const int* __restrict__ dst,
                                                       const float* __restrict__ ew,
                                                       int* __restrict__ cur1,
                                                       int2* __restrict__ pairs1,
                                                       int E, int nb, int aligned, int gA,
                                                       const float* __restrict__ x,
                                                       const float* __restrict__ W,
                                                       unsigned short* __restrict__ hbf,
                                                       int N) {
    __shared__ union SM {
        struct { int bcnt[MAXB1]; int bbase[MAXB1]; int brank[MAXB1]; } p;
        struct { float Ws[D * D]; float xs[64][D]; } g;   // 32 KB
    } sm;
    int tid = threadIdx.x;

    if ((int)blockIdx.x < gA) {
        // ---------- partition body: 8 edges/thread ----------
        for (int ib = blockIdx.x; ib < nb; ib += gA) {
            int base = ib * BATCHA;
            int blen = E - base;
            if (blen > BATCHA) blen = BATCHA;
            if (tid < MAXB1) { sm.p.bcnt[tid] = 0; sm.p.brank[tid] = 0; }
            __syncthreads();
            int dv[8], sv[8];
            float wv[8];
            int off = tid * 8;
            if (aligned && off + 8 <= blen) {
#pragma unroll
                for (int kk = 0; kk < 2; ++kk) {
                    int4 d4 = ((const int4*)(dst + base + off))[kk];
                    int4 s4 = ((const int4*)(src + base + off))[kk];
                    float4 w4 = ((const float4*)(ew + base + off))[kk];
                    dv[kk * 4 + 0] = d4.x; dv[kk * 4 + 1] = d4.y;
                    dv[kk * 4 + 2] = d4.z; dv[kk * 4 + 3] = d4.w;
                    sv[kk * 4 + 0] = s4.x; sv[kk * 4 + 1] = s4.y;
                    sv[kk * 4 + 2] = s4.z; sv[kk * 4 + 3] = s4.w;
                    wv[kk * 4 + 0] = w4.x; wv[kk * 4 + 1] = w4.y;
                    wv[kk * 4 + 2] = w4.z; wv[kk * 4 + 3] = w4.w;
                }
#pragma unroll
                for (int m = 0; m < 8; ++m) atomicAdd(&sm.p.bcnt[dv[m] >> BSH], 1);
            } else {
#pragma unroll
                for (int m = 0; m < 8; ++m) {
                    bool v = (off + m) < blen;
                    int e = base + off + m;
                    dv[m] = v ? __builtin_nontemporal_load(dst + e) : -1;
                    sv[m] = v ? __builtin_nontemporal_load(src + e) : 0;
                    wv[m] = v ? __builtin_nontemporal_load(ew + e) : 0.0f;
                    if (v) atomicAdd(&sm.p.bcnt[dv[m] >> BSH], 1);
                }
            }
            __syncthreads();
            if (tid < MAXB1 && sm.p.bcnt[tid] > 0)
                sm.p.bbase[tid] = atomicAdd(&cur1[tid * C1S], sm.p.bcnt[tid]);
            __syncthreads();
#pragma unroll
            for (int m = 0; m < 8; ++m) {
                if (dv[m] >= 0) {
                    int bin = dv[m] >> BSH;
                    int r = atomicAdd(&sm.p.brank[bin], 1);
                    pairs1[sm.p.bbase[bin] + r] =
                        make_int2(sv[m] | ((dv[m] & (NPB - 1)) << 17),
                                  __float_as_int(wv[m]));
                }
            }
            __syncthreads();
        }
    } else {
        // ---------- gemm body: h = x @ W -> bf16, 64 rows/block ----------
        int j = tid & 63;
        int g = tid >> 6;                        // 0..7
        int base = ((int)blockIdx.x - gA) * 64;
        for (int i = tid; i < D * D; i += 512) sm.g.Ws[i] = W[i];
        for (int rr = g; rr < 64; rr += 8) {
            int r = base + rr;
            if (r < N) sm.g.xs[rr][j] = x[(size_t)r * D + j];
        }
        __syncthreads();
        float wc[D];
#pragma unroll
        for (int k = 0; k < D; ++k) wc[k] = sm.g.Ws[k * D + j];
        for (int rr = g; rr < 64; rr += 8) {
            int r = base + rr;
            if (r < N) {
                float s0 = 0.0f, s1 = 0.0f, s2 = 0.0f, s3 = 0.0f;
#pragma unroll
                for (int k = 0; k < D; k += 4) {
                    s0 = fmaf(sm.g.xs[rr][k + 0], wc[k + 0], s0);
                    s1 = fmaf(sm.g.xs[rr][k + 1], wc[k + 1], s1);
                    s2 = fmaf(sm.g.xs[rr][k + 2], wc[k + 2], s2);
                    s3 = fmaf(sm.g.xs[rr][k + 3], wc[k + 3], s3);
                }
                hbf[(size_t)r * D + j] = f2bf((s0 + s1) + (s2 + s3));
            }
        }
    }
}

// ---------------- 4. per-bucket exact counting sort -> compact cw ----------------
// One block (512 thr) per bucket. cw = { src:17 | wq:15 }.

__global__ __launch_bounds__(512) void sortmerge_kernel(const int2* __restrict__ pairs1,
                                                        const int* __restrict__ off1,
                                                        unsigned* __restrict__ cw,
                                                        int* __restrict__ node_off,
                                                        int N, int B1) {
    __shared__ int lh[NPB];
    __shared__ int s[NPB];
    __shared__ int cur[NPB];
    int tid = threadIdx.x;
    int c = blockIdx.x;
    int e0 = off1[c], e1 = off1[c + 1];

    lh[tid] = 0;
    __syncthreads();

    // pass 1: per-node histogram (unroll-8 staged loads)
    for (int ib = e0; ib < e1; ib += 512 * 8) {
        long long pv[8];
#pragma unroll
        for (int m = 0; m < 8; ++m) {
            int i = ib + m * 512 + tid;
            pv[m] = (i < e1)
                ? __builtin_nontemporal_load((const long long*)(pairs1 + i))
                : -1LL;
        }
#pragma unroll
        for (int m = 0; m < 8; ++m) {
            int i = ib + m * 512 + tid;
            if (i < e1) atomicAdd(&lh[((int)pv[m] >> 17) & (NPB - 1)], 1);
        }
    }
    __syncthreads();

    // scan 512 (Hillis-Steele, 512 threads)
    s[tid] = lh[tid];
    __syncthreads();
    for (int o = 1; o < NPB; o <<= 1) {
        int t = (tid >= o) ? s[tid - o] : 0;
        __syncthreads();
        s[tid] += t;
        __syncthreads();
    }
    int ex = s[tid] - lh[tid];
    int gbase = c << BSH;
    if (gbase + tid <= N) node_off[gbase + tid] = e0 + ex;
    if (c == B1 - 1 && tid == 0) node_off[N] = e1;
    cur[tid] = ex;
    __syncthreads();

    // pass 2: scatter into node-sorted compact stream
    for (int ib = e0; ib < e1; ib += 512 * 8) {
        long long pv[8];
#pragma unroll
        for (int m = 0; m < 8; ++m) {
            int i = ib + m * 512 + tid;
            pv[m] = (i < e1)
                ? __builtin_nontemporal_load((const long long*)(pairs1 + i))
                : -1LL;
        }
#pragma unroll
        for (int m = 0; m < 8; ++m) {
            int i = ib + m * 512 + tid;
            if (i < e1) {
                int px = (int)pv[m];
                float w = __int_as_float((int)(pv[m] >> 32));
                int node = (px >> 17) & (NPB - 1);
                int pos = atomicAdd(&cur[node], 1);
                int wq = (int)fminf(fmaxf(w, 0.0f) * WSCALE + 0.5f, 32767.0f);
                cw[e0 + pos] = (unsigned)(px & 0x1FFFF) | ((unsigned)wq << 17);
            }
        }
    }
}

// ---------------- 5. accumulate: wave-per-node, 4 edge-groups x uint2, unroll-4 ----------------

__global__ __launch_bounds__(256) void accum_kernel(const unsigned* __restrict__ cw,
                                                    const int* __restrict__ node_off,
                                                    const unsigned short* __restrict__ hbf,
                                                    const float* __restrict__ bias,
                                                    float* __restrict__ out, int N) {
    int t = blockIdx.x * 256 + threadIdx.x;
    int n = t >> 6;
    int l = t & 63;
    if (n >= N) return;
    int eg = l >> 4;          // edge subgroup 0..3: edges i ≡ eg (mod 4)
    int cl = l & 15;          // column group: cols [4cl, 4cl+4)
    int base = node_off[n];
    int cnt = node_off[n + 1] - base;
    const unsigned* pp = cw + base;
    const unsigned short* hcol = hbf + cl * 4;

    float a0 = 0.0f, a1 = 0.0f, a2 = 0.0f, a3 = 0.0f;
    float degs = 0.0f;
    int i = eg;
    // 4 edges per lane per iteration (16 wave-edges)
    for (; i + 12 < cnt; i += 16) {
        unsigned va = pp[i];
        unsigned vb = pp[i + 4];
        unsigned vc = pp[i + 8];
        unsigned vd = pp[i + 12];
        uint2 ha = *(const uint2*)(hcol + (size_t)(va & 0x1FFFF) * D);
        uint2 hb = *(const uint2*)(hcol + (size_t)(vb & 0x1FFFF) * D);
        uint2 hc = *(const uint2*)(hcol + (size_t)(vc & 0x1FFFF) * D);
        uint2 hd = *(const uint2*)(hcol + (size_t)(vd & 0x1FFFF) * D);
        float wa = (float)(va >> 17) * WINV;
        float wb = (float)(vb >> 17) * WINV;
        float wc = (float)(vc >> 17) * WINV;
        float wd = (float)(vd >> 17) * WINV;
        degs += (wa + wb) + (wc + wd);
        a0 = fmaf(wa, bflo(ha.x), a0);
        a1 = fmaf(wa, bfhi(ha.x), a1);
        a2 = fmaf(wa, bflo(ha.y), a2);
        a3 = fmaf(wa, bfhi(ha.y), a3);
        a0 = fmaf(wb, bflo(hb.x), a0);
        a1 = fmaf(wb, bfhi(hb.x), a1);
        a2 = fmaf(wb, bflo(hb.y), a2);
        a3 = fmaf(wb, bfhi(hb.y), a3);
        a0 = fmaf(wc, bflo(hc.x), a0);
        a1 = fmaf(wc, bfhi(hc.x), a1);
        a2 = fmaf(wc, bflo(hc.y), a2);
        a3 = fmaf(wc, bfhi(hc.y), a3);
        a0 = fmaf(wd, bflo(hd.x), a0);
        a1 = fmaf(wd, bfhi(hd.x), a1);
        a2 = fmaf(wd, bflo(hd.y), a2);
        a3 = fmaf(wd, bfhi(hd.y), a3);
    }
    for (; i < cnt; i += 4) {
        unsigned v = pp[i];
        uint2 hv = *(const uint2*)(hcol + (size_t)(v & 0x1FFFF) * D);
        float w = (float)(v >> 17) * WINV;
        degs += w;
        a0 = fmaf(w, bflo(hv.x), a0);
        a1 = fmaf(w, bfhi(hv.x), a1);
        a2 = fmaf(w, bflo(hv.y), a2);
        a3 = fmaf(w, bfhi(hv.y), a3);
    }

    // reduce the 4 edge groups (lanes differing in bits 4,5)
    a0 += __shfl_xor(a0, 16); a0 += __shfl_xor(a0, 32);
    a1 += __shfl_xor(a1, 16); a1 += __shfl_xor(a1, 32);
    a2 += __shfl_xor(a2, 16); a2 += __shfl_xor(a2, 32);
    a3 += __shfl_xor(a3, 16); a3 += __shfl_xor(a3, 32);
    degs += __shfl_xor(degs, 16); degs += __shfl_xor(degs, 32);

    if (eg == 0) {
        // self loop (weight 1)
        uint2 hs = *(const uint2*)(hcol + (size_t)n * D);
        a0 += bflo(hs.x);
        a1 += bfhi(hs.x);
        a2 += bflo(hs.y);
        a3 += bfhi(hs.y);
        degs += 1.0f;
        float di = 1.0f / degs;   // degs >= 1 (ew >= 0)
        const float4 bv = *(const float4*)(bias + cl * 4);
        float4 o;
        o.x = fmaf(di, a0, bv.x);
        o.y = fmaf(di, a1, bv.y);
        o.z = fmaf(di, a2, bv.z);
        o.w = fmaf(di, a3, bv.w);
        __builtin_nontemporal_store(o.x, out + (size_t)n * D + cl * 4 + 0);
        __builtin_nontemporal_store(o.y, out + (size_t)n * D + cl * 4 + 1);
        __builtin_nontemporal_store(o.z, out + (size_t)n * D + cl * 4 + 2);
        __builtin_nontemporal_store(o.w, out + (size_t)n * D + cl * 4 + 3);
    }
}

// ---------------- fallback (atomic path) ----------------

__global__ __launch_bounds__(256) void deg_kernel(const int* __restrict__ dst,
                                                  const float* __restrict__ ew,
                                                  float* __restrict__ deg, int E) {
    int t = blockIdx.x * 256 + threadIdx.x;
    int stride = gridDim.x * 256;
    for (int e = t; e < E; e += stride) atomicAdd(&deg[dst[e]], ew[e]);
}

__global__ __launch_bounds__(256) void deginv_kernel(float* __restrict__ deg, int N) {
    int t = blockIdx.x * 256 + threadIdx.x;
    int stride = gridDim.x * 256;
    for (int n = t; n < N; n += stride) {
        float tot = deg[n] + 1.0f;
        deg[n] = (tot > 0.0f) ? (1.0f / tot) : 0.0f;
    }
}

__global__ __launch_bounds__(256) void gemm16f_kernel(const float* __restrict__ x,
                                                      const float* __restrict__ W,
                                                      float* __restrict__ h, int N) {
    __shared__ float Ws[D * D];
    __shared__ float xs[16][D];
    int tid = threadIdx.x;
    int j = tid & 63;
    int q = tid >> 6;
    int base = blockIdx.x * 16;
    for (int i = tid; i < D * D; i += 256) Ws[i] = W[i];
    for (int rr = q; rr < 16; rr += 4) {
        int r = base + rr;
        if (r < N) xs[rr][j] = x[(size_t)r * D + j];
    }
    __syncthreads();
    for (int rr = q; rr < 16; rr += 4) {
        int r = base + rr;
        if (r < N) {
            float sum = 0.0f;
#pragma unroll
            for (int k = 0; k < D; ++k) sum = fmaf(xs[rr][k], Ws[k * D + j], sum);
            h[(size_t)r * D + j] = sum;
        }
    }
}

__global__ __launch_bounds__(256) void init_kernel(const float* __restrict__ h,
                                                   const float* __restrict__ deginv,
                                                   const float* __restrict__ b,
                                                   float* __restrict__ out, int N) {
    int t = blockIdx.x * 256 + threadIdx.x;
    int stride = gridDim.x * 256;
    int nq = N * (D / 4);
    const float4* h4 = (const float4*)h;
    const float4* b4 = (const float4*)b;
    float4* o4 = (float4*)out;
    for (int q = t; q < nq; q += stride) {
        int n = q >> 4;
        int c4 = q & 15;
        float4 hv = h4[q];
        float4 bv = b4[c4];
        float di = deginv[n];
        float4 o;
        o.x = bv.x + di * hv.x;
        o.y = bv.y + di * hv.y;
        o.z = bv.z + di * hv.z;
        o.w = bv.w + di * hv.w;
        o4[q] = o;
    }
}

__global__ __launch_bounds__(256) void scatter_kernel(const int* __restrict__ src,
                                                      const int* __restrict__ dst,
                                                      const float* __restrict__ ew,
                                                      const float* __restrict__ deginv,
                                                      const float* __restrict__ h,
                                                      float* __restrict__ out, int E) {
    int t = blockIdx.x * 256 + threadIdx.x;
    int wave = t >> 6;
    int lane = t & 63;
    int nwaves = (gridDim.x * 256) >> 6;
    for (int e = wave; e < E; e += nwaves) {
        int s = src[e];
        int d = dst[e];
        float norm = deginv[d] * ew[e];
        atomicAdd(&out[d * D + lane], norm * h[s * D + lane]);
    }
}

// ---------------- launcher ----------------

extern "C" void kernel_launch(void* const* d_in, const int* in_sizes, int n_in,
                              void* d_out, int out_size, void* d_ws, size_t ws_size,
                              hipStream_t stream) {
    const float* x  = (const float*)d_in[0];
    const int*   ei = (const int*)d_in[1];
    const float* ew = (const float*)d_in[2];
    const float* W  = (const float*)d_in[3];
    const float* b  = (const float*)d_in[4];
    float* out = (float*)d_out;

    int N = in_sizes[0] / D;
    int E = in_sizes[2];
    const int* srcp = ei;
    const int* dstp = ei + E;

    int B1 = (N + NPB - 1) >> BSH;

    // ws ints: hist[256] | off1[320] | cur1[256*C1S] | node_off[N+64]
    // then pairs1 (E*8), hbf (N*D*2), cw (E*4)
    size_t ints_n = 256 + 320 + (size_t)MAXB1 * C1S + ((size_t)N + 64);
    size_t p1_off  = ((ints_n * 4) + 255) & ~(size_t)255;
    size_t hbf_off = (p1_off + (size_t)E * 8 + 255) & ~(size_t)255;
    size_t cw_off  = (hbf_off + (size_t)N * D * 2 + 255) & ~(size_t)255;
    size_t need = cw_off + (size_t)E * 4;

    if (N <= 131072 && ws_size >= need) {
        int* hist     = (int*)d_ws;
        int* off1     = hist + 256;
        int* cur1     = off1 + 320;
        int* node_off = cur1 + (size_t)MAXB1 * C1S;
        int2* pairs1  = (int2*)((char*)d_ws + p1_off);
        unsigned short* hbf = (unsigned short*)((char*)d_ws + hbf_off);
        unsigned* cw  = (unsigned*)((char*)d_ws + cw_off);

        int aligned = (((E & 3) == 0) && (((size_t)dstp & 15) == 0)) ? 1 : 0;

        hipMemsetAsync(hist, 0, 256 * 4, stream);
        hist_kernel<<<512, 256, 0, stream>>>(dstp, hist, E, B1);
        scan_kernel<<<1, 256, 0, stream>>>(hist, off1, cur1, B1, E);
        int nb = (E + BATCHA - 1) / BATCHA;
        int gA = nb < 2048 ? nb : 2048;
        int gG = (N + 63) / 64;
        partgemm_kernel<<<gA + gG, 512, 0, stream>>>(srcp, dstp, ew, cur1, pairs1,
                                                     E, nb, aligned, gA, x, W, hbf, N);
        sortmerge_kernel<<<B1, 512, 0, stream>>>(pairs1, off1, cw, node_off, N, B1);
        accum_kernel<<<(N + 3) / 4, 256, 0, stream>>>(cw, node_off, hbf, b, out, N);
    } else {
        // fallback: atomic scatter path
        size_t Npad = ((size_t)N + 63) & ~(size_t)63;
        float* deg = (float*)d_ws;
        float* h = deg + Npad;
        hipMemsetAsync(deg, 0, (size_t)N * sizeof(float), stream);
        deg_kernel<<<2048, 256, 0, stream>>>(dstp, ew, deg, E);
        deginv_kernel<<<(N + 255) / 256, 256, 0, stream>>>(deg, N);
        gemm16f_kernel<<<(N + 15) / 16, 256, 0, stream>>>(x, W, h, N);
        init_kernel<<<2048, 256, 0, stream>>>(h, deg, b, out, N);
        scatter_kernel<<<2048, 256, 0, stream>>>(srcp, dstp, ew, deg, h, out, E);
    }
}

// Round 16
// 175.987 us; speedup vs baseline: 1.0338x; 1.0338x over previous
//
#include <hip/hip_runtime.h>

// GiGCNConv: out[d] = b + (1/deg[d]) * ( h[d] + sum_{e:(s->d)} ew[e]*h[s] )
//   h = x @ W,  deg[d] = 1 + sum_{e:dst==d} ew[e]
//
// Round-16 = round-15 with partgemm's partition body writing through an
// LDS-sorted staging tile: rank -> scan -> LDS bin-sorted tile -> coalesced
// copy-out (runs of ~16 edges = 128B per bin). Rounds 14/15 measured ~70us
// invariant under occupancy changes => scattered 8B stores were issue-bound.
//
// Inputs: x f32[N*64], edge_index i32[2*E], edge_weight f32[E],
//         W f32[64*64], b f32[64].  Output f32[N*64].

#define D 64
#define BSH 9                // 512 nodes per bucket
#define NPB 512
#define MAXB1 256            // N <= 131072
#define BATCHA 4096
#define C1S 32
#define WSCALE 8192.0f
#define WINV (1.0f / 8192.0f)

static __device__ __forceinline__ unsigned short f2bf(float f) {
    unsigned u = __float_as_uint(f);
    u += 0x7FFFu + ((u >> 16) & 1u);
    return (unsigned short)(u >> 16);
}
static __device__ __forceinline__ float bflo(unsigned u) {
    return __uint_as_float(u << 16);
}
static __device__ __forceinline__ float bfhi(unsigned u) {
    return __uint_as_float(u & 0xFFFF0000u);
}

// ---------------- 1. bucket histogram ----------------

__global__ __launch_bounds__(256) void hist_kernel(const int* __restrict__ dst,
                                                   int* __restrict__ hist, int E, int B1) {
    __shared__ int lh[MAXB1];
    int tid = threadIdx.x;
    if (tid < MAXB1) lh[tid] = 0;
    __syncthreads();
    int t = blockIdx.x * 256 + tid;
    int stride = gridDim.x * 256;
    if ((E & 3) == 0 && (((size_t)dst & 15) == 0)) {
        const int4* d4 = (const int4*)dst;
        int n4 = E >> 2;
        for (int e = t; e < n4; e += stride) {
            int4 v = d4[e];
            atomicAdd(&lh[v.x >> BSH], 1);
            atomicAdd(&lh[v.y >> BSH], 1);
            atomicAdd(&lh[v.z >> BSH], 1);
            atomicAdd(&lh[v.w >> BSH], 1);
        }
    } else {
        for (int e = t; e < E; e += stride) {
            int d = __builtin_nontemporal_load(dst + e);
            atomicAdd(&lh[d >> BSH], 1);
        }
    }
    __syncthreads();
    if (tid < B1) {
        int v = lh[tid];
        if (v) atomicAdd(&hist[tid], v);
    }
}

// ---------------- 2. scan (single block, <=256 bins) ----------------

__global__ __launch_bounds__(256) void scan_kernel(const int* __restrict__ hist,
                                                   int* __restrict__ off1,
                                                   int* __restrict__ cur1, int B1, int E) {
    __shared__ int s[256];
    int tid = threadIdx.x;
    int v = (tid < B1) ? hist[tid] : 0;
    s[tid] = v;
    __syncthreads();
    for (int o = 1; o < 256; o <<= 1) {
        int t = (tid >= o) ? s[tid - o] : 0;
        __syncthreads();
        s[tid] += t;
        __syncthreads();
    }
    if (tid < B1) {
        int ex = s[tid] - v;
        off1[tid] = ex;
        cur1[tid * C1S] = ex;
    }
    if (tid == 0) off1[B1] = E;
}

// ---------------- 3. FUSED: partA (blocks < gA) + gemmW (blocks >= gA) ----------------
// 512 threads. pair1 = { src | (dst & 511) << 17 , ew }   (src <= 17 bits)
// Partition body stages the batch bin-sorted in LDS, then copies out
// coalesced (per-bin runs are contiguous in both LDS and global).

__global__ __launch_bounds__(512) void partgemm_kernel(const int* __restrict__ src,
                                                       const int* __restrict__ dst,
                                                       const float* __restrict__ ew,
                                                       int* __restrict__ cur1,
                                                       int2* __restrict__ pairs1,
                                                       int E, int nb, int aligned, int gA,
                                                       const float* __restrict__ x,
                                                       const float* __restrict__ W,
                                                       unsigned short* __restrict__ hbf,
                                                       int N) {
    __shared__ union SM {
        struct {
            int2 tile[BATCHA];            // 32 KB bin-sorted pairs
            unsigned char binof[BATCHA];  // 4 KB bin id per sorted slot
            int bcnt[MAXB1];              // batch bin counts / ranks
            int lbase[MAXB1];             // exclusive scan (LDS base)
            int bbase[MAXB1];             // global base (cursor result)
            int scan_[MAXB1];             // scan scratch
        } p;                              // ~41 KB
        struct { float Ws[D * D]; float xs[64][D]; } g;   // 32 KB
    } sm;
    int tid = threadIdx.x;

    if ((int)blockIdx.x < gA) {
        // ---------- partition body: 8 edges/thread, LDS-sorted staging ----------
        for (int ib = blockIdx.x; ib < nb; ib += gA) {
            int base = ib * BATCHA;
            int blen = E - base;
            if (blen > BATCHA) blen = BATCHA;
            if (tid < MAXB1) sm.p.bcnt[tid] = 0;
            __syncthreads();

            int bv[8], sv[8], rv[8];
            float wv[8];
            int off = tid * 8;
            if (aligned && off + 8 <= blen) {
#pragma unroll
                for (int kk = 0; kk < 2; ++kk) {
                    int4 d4 = ((const int4*)(dst + base + off))[kk];
                    int4 s4 = ((const int4*)(src + base + off))[kk];
                    float4 w4 = ((const float4*)(ew + base + off))[kk];
                    int dd[4] = {d4.x, d4.y, d4.z, d4.w};
                    int ss[4] = {s4.x, s4.y, s4.z, s4.w};
                    float ww[4] = {w4.x, w4.y, w4.z, w4.w};
#pragma unroll
                    for (int q = 0; q < 4; ++q) {
                        int m = kk * 4 + q;
                        sv[m] = ss[q] | ((dd[q] & (NPB - 1)) << 17);
                        wv[m] = ww[q];
                        bv[m] = dd[q] >> BSH;
                    }
                }
#pragma unroll
                for (int m = 0; m < 8; ++m)
                    rv[m] = atomicAdd(&sm.p.bcnt[bv[m]], 1);
            } else {
#pragma unroll
                for (int m = 0; m < 8; ++m) {
                    bool v = (off + m) < blen;
                    int e = base + off + m;
                    if (v) {
                        int d = __builtin_nontemporal_load(dst + e);
                        int s = __builtin_nontemporal_load(src + e);
                        float w = __builtin_nontemporal_load(ew + e);
                        sv[m] = s | ((d & (NPB - 1)) << 17);
                        wv[m] = w;
                        bv[m] = d >> BSH;
                        rv[m] = atomicAdd(&sm.p.bcnt[bv[m]], 1);
                    } else {
                        bv[m] = -1;
                    }
                }
            }
            __syncthreads();

            // exclusive scan of bcnt over 256 bins (Hillis-Steele in scan_)
            if (tid < MAXB1) sm.p.scan_[tid] = sm.p.bcnt[tid];
            __syncthreads();
            for (int o = 1; o < MAXB1; o <<= 1) {
                int t = 0;
                if (tid < MAXB1 && tid >= o) t = sm.p.scan_[tid - o];
                __syncthreads();
                if (tid < MAXB1) sm.p.scan_[tid] += t;
                __syncthreads();
            }
            if (tid < MAXB1) {
                sm.p.lbase[tid] = sm.p.scan_[tid] - sm.p.bcnt[tid];
                if (sm.p.bcnt[tid] > 0)
                    sm.p.bbase[tid] = atomicAdd(&cur1[tid * C1S], sm.p.bcnt[tid]);
            }
            __syncthreads();

            // stage: write pairs bin-sorted into LDS
#pragma unroll
            for (int m = 0; m < 8; ++m) {
                if (bv[m] >= 0) {
                    int slot = sm.p.lbase[bv[m]] + rv[m];
                    sm.p.tile[slot] = make_int2(sv[m], __float_as_int(wv[m]));
                    sm.p.binof[slot] = (unsigned char)bv[m];
                }
            }
            __syncthreads();

            // copy out: consecutive slots in a bin -> consecutive global addrs
            for (int i = tid; i < blen; i += 512) {
                int2 p = sm.p.tile[i];
                int bin = sm.p.binof[i];
                pairs1[sm.p.bbase[bin] + (i - sm.p.lbase[bin])] = p;
            }
            __syncthreads();
        }
    } else {
        // ---------- gemm body: h = x @ W -> bf16, 64 rows/block ----------
        int j = tid & 63;
        int g = tid >> 6;                        // 0..7
        int base = ((int)blockIdx.x - gA) * 64;
        for (int i = tid; i < D * D; i += 512) sm.g.Ws[i] = W[i];
        for (int rr = g; rr < 64; rr += 8) {
            int r = base + rr;
            if (r < N) sm.g.xs[rr][j] = x[(size_t)r * D + j];
        }
        __syncthreads();
        float wc[D];
#pragma unroll
        for (int k = 0; k < D; ++k) wc[k] = sm.g.Ws[k * D + j];
        for (int rr = g; rr < 64; rr += 8) {
            int r = base + rr;
            if (r < N) {
                float s0 = 0.0f, s1 = 0.0f, s2 = 0.0f, s3 = 0.0f;
#pragma unroll
                for (int k = 0; k < D; k += 4) {
                    s0 = fmaf(sm.g.xs[rr][k + 0], wc[k + 0], s0);
                    s1 = fmaf(sm.g.xs[rr][k + 1], wc[k + 1], s1);
                    s2 = fmaf(sm.g.xs[rr][k + 2], wc[k + 2], s2);
                    s3 = fmaf(sm.g.xs[rr][k + 3], wc[k + 3], s3);
                }
                hbf[(size_t)r * D + j] = f2bf((s0 + s1) + (s2 + s3));
            }
        }
    }
}

// ---------------- 4. per-bucket exact counting sort -> compact cw ----------------
// One block (512 thr) per bucket. cw = { src:17 | wq:15 }.

__global__ __launch_bounds__(512) void sortmerge_kernel(const int2* __restrict__ pairs1,
                                                        const int* __restrict__ off1,
                                                        unsigned* __restrict__ cw,
                                                        int* __restrict__ node_off,
                                                        int N, int B1) {
    __shared__ int lh[NPB];
    __shared__ int s[NPB];
    __shared__ int cur[NPB];
    int tid = threadIdx.x;
    int c = blockIdx.x;
    int e0 = off1[c], e1 = off1[c + 1];

    lh[tid] = 0;
    __syncthreads();

    // pass 1: per-node histogram (unroll-8 staged loads)
    for (int ib = e0; ib < e1; ib += 512 * 8) {
        long long pv[8];
#pragma unroll
        for (int m = 0; m < 8; ++m) {
            int i = ib + m * 512 + tid;
            pv[m] = (i < e1)
                ? __builtin_nontemporal_load((const long long*)(pairs1 + i))
                : -1LL;
        }
#pragma unroll
        for (int m = 0; m < 8; ++m) {
            int i = ib + m * 512 + tid;
            if (i < e1) atomicAdd(&lh[((int)pv[m] >> 17) & (NPB - 1)], 1);
        }
    }
    __syncthreads();

    // scan 512 (Hillis-Steele, 512 threads)
    s[tid] = lh[tid];
    __syncthreads();
    for (int o = 1; o < NPB; o <<= 1) {
        int t = (tid >= o) ? s[tid - o] : 0;
        __syncthreads();
        s[tid] += t;
        __syncthreads();
    }
    int ex = s[tid] - lh[tid];
    int gbase = c << BSH;
    if (gbase + tid <= N) node_off[gbase + tid] = e0 + ex;
    if (c == B1 - 1 && tid == 0) node_off[N] = e1;
    cur[tid] = ex;
    __syncthreads();

    // pass 2: scatter into node-sorted compact stream
    for (int ib = e0; ib < e1; ib += 512 * 8) {
        long long pv[8];
#pragma unroll
        for (int m = 0; m < 8; ++m) {
            int i = ib + m * 512 + tid;
            pv[m] = (i < e1)
                ? __builtin_nontemporal_load((const long long*)(pairs1 + i))
                : -1LL;
        }
#pragma unroll
        for (int m = 0; m < 8; ++m) {
            int i = ib + m * 512 + tid;
            if (i < e1) {
                int px = (int)pv[m];
                float w = __int_as_float((int)(pv[m] >> 32));
                int node = (px >> 17) & (NPB - 1);
                int pos = atomicAdd(&cur[node], 1);
                int wq = (int)fminf(fmaxf(w, 0.0f) * WSCALE + 0.5f, 32767.0f);
                cw[e0 + pos] = (unsigned)(px & 0x1FFFF) | ((unsigned)wq << 17);
            }
        }
    }
}

// ---------------- 5. accumulate: wave-per-node, 4 edge-groups x uint2, unroll-4 ----------------

__global__ __launch_bounds__(256) void accum_kernel(const unsigned* __restrict__ cw,
                                                    const int* __restrict__ node_off,
                                                    const unsigned short* __restrict__ hbf,
                                                    const float* __restrict__ bias,
                                                    float* __restrict__ out, int N) {
    int t = blockIdx.x * 256 + threadIdx.x;
    int n = t >> 6;
    int l = t & 63;
    if (n >= N) return;
    int eg = l >> 4;          // edge subgroup 0..3: edges i ≡ eg (mod 4)
    int cl = l & 15;          // column group: cols [4cl, 4cl+4)
    int base = node_off[n];
    int cnt = node_off[n + 1] - base;
    const unsigned* pp = cw + base;
    const unsigned short* hcol = hbf + cl * 4;

    float a0 = 0.0f, a1 = 0.0f, a2 = 0.0f, a3 = 0.0f;
    float degs = 0.0f;
    int i = eg;
    // 4 edges per lane per iteration (16 wave-edges)
    for (; i + 12 < cnt; i += 16) {
        unsigned va = pp[i];
        unsigned vb = pp[i + 4];
        unsigned vc = pp[i + 8];
        unsigned vd = pp[i + 12];
        uint2 ha = *(const uint2*)(hcol + (size_t)(va & 0x1FFFF) * D);
        uint2 hb = *(const uint2*)(hcol + (size_t)(vb & 0x1FFFF) * D);
        uint2 hc = *(const uint2*)(hcol + (size_t)(vc & 0x1FFFF) * D);
        uint2 hd = *(const uint2*)(hcol + (size_t)(vd & 0x1FFFF) * D);
        float wa = (float)(va >> 17) * WINV;
        float wb = (float)(vb >> 17) * WINV;
        float wc = (float)(vc >> 17) * WINV;
        float wd = (float)(vd >> 17) * WINV;
        degs += (wa + wb) + (wc + wd);
        a0 = fmaf(wa, bflo(ha.x), a0);
        a1 = fmaf(wa, bfhi(ha.x), a1);
        a2 = fmaf(wa, bflo(ha.y), a2);
        a3 = fmaf(wa, bfhi(ha.y), a3);
        a0 = fmaf(wb, bflo(hb.x), a0);
        a1 = fmaf(wb, bfhi(hb.x), a1);
        a2 = fmaf(wb, bflo(hb.y), a2);
        a3 = fmaf(wb, bfhi(hb.y), a3);
        a0 = fmaf(wc, bflo(hc.x), a0);
        a1 = fmaf(wc, bfhi(hc.x), a1);
        a2 = fmaf(wc, bflo(hc.y), a2);
        a3 = fmaf(wc, bfhi(hc.y), a3);
        a0 = fmaf(wd, bflo(hd.x), a0);
        a1 = fmaf(wd, bfhi(hd.x), a1);
        a2 = fmaf(wd, bflo(hd.y), a2);
        a3 = fmaf(wd, bfhi(hd.y), a3);
    }
    for (; i < cnt; i += 4) {
        unsigned v = pp[i];
        uint2 hv = *(const uint2*)(hcol + (size_t)(v & 0x1FFFF) * D);
        float w = (float)(v >> 17) * WINV;
        degs += w;
        a0 = fmaf(w, bflo(hv.x), a0);
        a1 = fmaf(w, bfhi(hv.x), a1);
        a2 = fmaf(w, bflo(hv.y), a2);
        a3 = fmaf(w, bfhi(hv.y), a3);
    }

    // reduce the 4 edge groups (lanes differing in bits 4,5)
    a0 += __shfl_xor(a0, 16); a0 += __shfl_xor(a0, 32);
    a1 += __shfl_xor(a1, 16); a1 += __shfl_xor(a1, 32);
    a2 += __shfl_xor(a2, 16); a2 += __shfl_xor(a2, 32);
    a3 += __shfl_xor(a3, 16); a3 += __shfl_xor(a3, 32);
    degs += __shfl_xor(degs, 16); degs += __shfl_xor(degs, 32);

    if (eg == 0) {
        // self loop (weight 1)
        uint2 hs = *(const uint2*)(hcol + (size_t)n * D);
        a0 += bflo(hs.x);
        a1 += bfhi(hs.x);
        a2 += bflo(hs.y);
        a3 += bfhi(hs.y);
        degs += 1.0f;
        float di = 1.0f / degs;   // degs >= 1 (ew >= 0)
        const float4 bv = *(const float4*)(bias + cl * 4);
        float4 o;
        o.x = fmaf(di, a0, bv.x);
        o.y = fmaf(di, a1, bv.y);
        o.z = fmaf(di, a2, bv.z);
        o.w = fmaf(di, a3, bv.w);
        __builtin_nontemporal_store(o.x, out + (size_t)n * D + cl * 4 + 0);
        __builtin_nontemporal_store(o.y, out + (size_t)n * D + cl * 4 + 1);
        __builtin_nontemporal_store(o.z, out + (size_t)n * D + cl * 4 + 2);
        __builtin_nontemporal_store(o.w, out + (size_t)n * D + cl * 4 + 3);
    }
}

// ---------------- fallback (atomic path) ----------------

__global__ __launch_bounds__(256) void deg_kernel(const int* __restrict__ dst,
                                                  const float* __restrict__ ew,
                                                  float* __restrict__ deg, int E) {
    int t = blockIdx.x * 256 + threadIdx.x;
    int stride = gridDim.x * 256;
    for (int e = t; e < E; e += stride) atomicAdd(&deg[dst[e]], ew[e]);
}

__global__ __launch_bounds__(256) void deginv_kernel(float* __restrict__ deg, int N) {
    int t = blockIdx.x * 256 + threadIdx.x;
    int stride = gridDim.x * 256;
    for (int n = t; n < N; n += stride) {
        float tot = deg[n] + 1.0f;
        deg[n] = (tot > 0.0f) ? (1.0f / tot) : 0.0f;
    }
}

__global__ __launch_bounds__(256) void gemm16f_kernel(const float* __restrict__ x,
                                                      const float* __restrict__ W,
                                                      float* __restrict__ h, int N) {
    __shared__ float Ws[D * D];
    __shared__ float xs[16][D];
    int tid = threadIdx.x;
    int j = tid & 63;
    int q = tid >> 6;
    int base = blockIdx.x * 16;
    for (int i = tid; i < D * D; i += 256) Ws[i] = W[i];
    for (int rr = q; rr < 16; rr += 4) {
        int r = base + rr;
        if (r < N) xs[rr][j] = x[(size_t)r * D + j];
    }
    __syncthreads();
    for (int rr = q; rr < 16; rr += 4) {
        int r = base + rr;
        if (r < N) {
            float sum = 0.0f;
#pragma unroll
            for (int k = 0; k < D; ++k) sum = fmaf(xs[rr][k], Ws[k * D + j], sum);
            h[(size_t)r * D + j] = sum;
        }
    }
}

__global__ __launch_bounds__(256) void init_kernel(const float* __restrict__ h,
                                                   const float* __restrict__ deginv,
                                                   const float* __restrict__ b,
                                                   float* __restrict__ out, int N) {
    int t = blockIdx.x * 256 + threadIdx.x;
    int stride = gridDim.x * 256;
    int nq = N * (D / 4);
    const float4* h4 = (const float4*)h;
    const float4* b4 = (const float4*)b;
    float4* o4 = (float4*)out;
    for (int q = t; q < nq; q += stride) {
        int n = q >> 4;
        int c4 = q & 15;
        float4 hv = h4[q];
        float4 bv = b4[c4];
        float di = deginv[n];
        float4 o;
        o.x = bv.x + di * hv.x;
        o.y = bv.y + di * hv.y;
        o.z = bv.z + di * hv.z;
        o.w = bv.w + di * hv.w;
        o4[q] = o;
    }
}

__global__ __launch_bounds__(256) void scatter_kernel(const int* __restrict__ src,
                                                      const int* __restrict__ dst,
                                                      const float* __restrict__ ew,
                                                      const float* __restrict__ deginv,
                                                      const float* __restrict__ h,
                                                      float* __restrict__ out, int E) {
    int t = blockIdx.x * 256 + threadIdx.x;
    int wave = t >> 6;
    int lane = t & 63;
    int nwaves = (gridDim.x * 256) >> 6;
    for (int e = wave; e < E; e += nwaves) {
        int s = src[e];
        int d = dst[e];
        float norm = deginv[d] * ew[e];
        atomicAdd(&out[d * D + lane], norm * h[s * D + lane]);
    }
}

// ---------------- launcher ----------------

extern "C" void kernel_launch(void* const* d_in, const int* in_sizes, int n_in,
                              void* d_out, int out_size, void* d_ws, size_t ws_size,
                              hipStream_t stream) {
    const float* x  = (const float*)d_in[0];
    const int*   ei = (const int*)d_in[1];
    const float* ew = (const float*)d_in[2];
    const float* W  = (const float*)d_in[3];
    const float* b  = (const float*)d_in[4];
    float* out = (float*)d_out;

    int N = in_sizes[0] / D;
    int E = in_sizes[2];
    const int* srcp = ei;
    const int* dstp = ei + E;

    int B1 = (N + NPB - 1) >> BSH;

    // ws ints: hist[256] | off1[320] | cur1[256*C1S] | node_off[N+64]
    // then pairs1 (E*8), hbf (N*D*2), cw (E*4)
    size_t ints_n = 256 + 320 + (size_t)MAXB1 * C1S + ((size_t)N + 64);
    size_t p1_off  = ((ints_n * 4) + 255) & ~(size_t)255;
    size_t hbf_off = (p1_off + (size_t)E * 8 + 255) & ~(size_t)255;
    size_t cw_off  = (hbf_off + (size_t)N * D * 2 + 255) & ~(size_t)255;
    size_t need = cw_off + (size_t)E * 4;

    if (N <= 131072 && ws_size >= need) {
        int* hist     = (int*)d_ws;
        int* off1     = hist + 256;
        int* cur1     = off1 + 320;
        int* node_off = cur1 + (size_t)MAXB1 * C1S;
        int2* pairs1  = (int2*)((char*)d_ws + p1_off);
        unsigned short* hbf = (unsigned short*)((char*)d_ws + hbf_off);
        unsigned* cw  = (unsigned*)((char*)d_ws + cw_off);

        int aligned = (((E & 3) == 0) && (((size_t)dstp & 15) == 0)) ? 1 : 0;

        hipMemsetAsync(hist, 0, 256 * 4, stream);
        hist_kernel<<<512, 256, 0, stream>>>(dstp, hist, E, B1);
        scan_kernel<<<1, 256, 0, stream>>>(hist, off1, cur1, B1, E);
        int nb = (E + BATCHA - 1) / BATCHA;
        int gA = nb < 2048 ? nb : 2048;
        int gG = (N + 63) / 64;
        partgemm_kernel<<<gA + gG, 512, 0, stream>>>(srcp, dstp, ew, cur1, pairs1,
                                                     E, nb, aligned, gA, x, W, hbf, N);
        sortmerge_kernel<<<B1, 512, 0, stream>>>(pairs1, off1, cw, node_off, N, B1);
        accum_kernel<<<(N + 3) / 4, 256, 0, stream>>>(cw, node_off, hbf, b, out, N);
    } else {
        // fallback: atomic scatter path
        size_t Npad = ((size_t)N + 63) & ~(size_t)63;
        float* deg = (float*)d_ws;
        float* h = deg + Npad;
        hipMemsetAsync(deg, 0, (size_t)N * sizeof(float), stream);
        deg_kernel<<<2048, 256, 0, stream>>>(dstp, ew, deg, E);
        deginv_kernel<<<(N + 255) / 256, 256, 0, stream>>>(deg, N);
        gemm16f_kernel<<<(N + 15) / 16, 256, 0, stream>>>(x, W, h, N);
        init_kernel<<<2048, 256, 0, stream>>>(h, deg, b, out, N);
        scatter_kernel<<<2048, 256, 0, stream>>>(srcp, dstp, ew, deg, h, out, E);
    }
}

// Round 17
// 173.858 us; speedup vs baseline: 1.0464x; 1.0122x over previous
//
#include <hip/hip_runtime.h>

// GiGCNConv: out[d] = b + (1/deg[d]) * ( h[d] + sum_{e:(s->d)} ew[e]*h[s] )
//   h = x @ W,  deg[d] = 1 + sum_{e:dst==d} ew[e]
//
// Round-17 = round-16 with partgemm block roles BRESENHAM-INTERLEAVED:
//   round-16's fused kernel dispatched all partition blocks first -> they
//   filled every CU and gemm ran after them (measured: partgemm ~= part+gemm
//   serial, 67us, occupancy 36%). Interleaving roles (exactly gA partition,
//   gG gemm, evenly spread over the grid) co-schedules latency-bound
//   partition with VALU-bound gemm on every CU from t=0.
//
// Inputs: x f32[N*64], edge_index i32[2*E], edge_weight f32[E],
//         W f32[64*64], b f32[64].  Output f32[N*64].

#define D 64
#define BSH 9                // 512 nodes per bucket
#define NPB 512
#define MAXB1 256            // N <= 131072
#define BATCHA 4096
#define C1S 32
#define WSCALE 8192.0f
#define WINV (1.0f / 8192.0f)

static __device__ __forceinline__ unsigned short f2bf(float f) {
    unsigned u = __float_as_uint(f);
    u += 0x7FFFu + ((u >> 16) & 1u);
    return (unsigned short)(u >> 16);
}
static __device__ __forceinline__ float bflo(unsigned u) {
    return __uint_as_float(u << 16);
}
static __device__ __forceinline__ float bfhi(unsigned u) {
    return __uint_as_float(u & 0xFFFF0000u);
}

// ---------------- 1. bucket histogram ----------------

__global__ __launch_bounds__(256) void hist_kernel(const int* __restrict__ dst,
                                                   int* __restrict__ hist, int E, int B1) {
    __shared__ int lh[MAXB1];
    int tid = threadIdx.x;
    if (tid < MAXB1) lh[tid] = 0;
    __syncthreads();
    int t = blockIdx.x * 256 + tid;
    int stride = gridDim.x * 256;
    if ((E & 3) == 0 && (((size_t)dst & 15) == 0)) {
        const int4* d4 = (const int4*)dst;
        int n4 = E >> 2;
        for (int e = t; e < n4; e += stride) {
            int4 v = d4[e];
            atomicAdd(&lh[v.x >> BSH], 1);
            atomicAdd(&lh[v.y >> BSH], 1);
            atomicAdd(&lh[v.z >> BSH], 1);
            atomicAdd(&lh[v.w >> BSH], 1);
        }
    } else {
        for (int e = t; e < E; e += stride) {
            int d = __builtin_nontemporal_load(dst + e);
            atomicAdd(&lh[d >> BSH], 1);
        }
    }
    __syncthreads();
    if (tid < B1) {
        int v = lh[tid];
        if (v) atomicAdd(&hist[tid], v);
    }
}

// ---------------- 2. scan (single block, <=256 bins) ----------------

__global__ __launch_bounds__(256) void scan_kernel(const int* __restrict__ hist,
                                                   int* __restrict__ off1,
                                                   int* __restrict__ cur1, int B1, int E) {
    __shared__ int s[256];
    int tid = threadIdx.x;
    int v = (tid < B1) ? hist[tid] : 0;
    s[tid] = v;
    __syncthreads();
    for (int o = 1; o < 256; o <<= 1) {
        int t = (tid >= o) ? s[tid - o] : 0;
        __syncthreads();
        s[tid] += t;
        __syncthreads();
    }
    if (tid < B1) {
        int ex = s[tid] - v;
        off1[tid] = ex;
        cur1[tid * C1S] = ex;
    }
    if (tid == 0) off1[B1] = E;
}

// ---------------- 3. FUSED (interleaved roles): partition + gemm ----------------
// 512 threads. pair1 = { src | (dst & 511) << 17 , ew }   (src <= 17 bits)

__global__ __launch_bounds__(512) void partgemm_kernel(const int* __restrict__ src,
                                                       const int* __restrict__ dst,
                                                       const float* __restrict__ ew,
                                                       int* __restrict__ cur1,
                                                       int2* __restrict__ pairs1,
                                                       int E, int nb, int aligned,
                                                       int gA, int total,
                                                       const float* __restrict__ x,
                                                       const float* __restrict__ W,
                                                       unsigned short* __restrict__ hbf,
                                                       int N) {
    __shared__ union SM {
        struct {
            int2 tile[BATCHA];            // 32 KB bin-sorted pairs
            unsigned char binof[BATCHA];  // 4 KB bin id per sorted slot
            int bcnt[MAXB1];
            int lbase[MAXB1];
            int bbase[MAXB1];
            int scan_[MAXB1];
        } p;                              // ~41 KB
        struct { float Ws[D * D]; float xs[64][D]; } g;   // 32 KB
    } sm;
    int tid = threadIdx.x;

    // Bresenham role assignment: exactly gA partition blocks, evenly spread.
    long long pid = (long long)blockIdx.x;
    int c = (int)((pid * gA) / total);
    bool isPart = ((int)(((pid + 1) * gA) / total) > c);

    if (isPart) {
        // ---------- partition body: 8 edges/thread, LDS-sorted staging ----------
        for (int ib = c; ib < nb; ib += gA) {
            int base = ib * BATCHA;
            int blen = E - base;
            if (blen > BATCHA) blen = BATCHA;
            if (tid < MAXB1) sm.p.bcnt[tid] = 0;
            __syncthreads();

            int bv[8], sv[8], rv[8];
            float wv[8];
            int off = tid * 8;
            if (aligned && off + 8 <= blen) {
#pragma unroll
                for (int kk = 0; kk < 2; ++kk) {
                    int4 d4 = ((const int4*)(dst + base + off))[kk];
                    int4 s4 = ((const int4*)(src + base + off))[kk];
                    float4 w4 = ((const float4*)(ew + base + off))[kk];
                    int dd[4] = {d4.x, d4.y, d4.z, d4.w};
                    int ss[4] = {s4.x, s4.y, s4.z, s4.w};
                    float ww[4] = {w4.x, w4.y, w4.z, w4.w};
#pragma unroll
                    for (int q = 0; q < 4; ++q) {
                        int m = kk * 4 + q;
                        sv[m] = ss[q] | ((dd[q] & (NPB - 1)) << 17);
                        wv[m] = ww[q];
                        bv[m] = dd[q] >> BSH;
                    }
                }
#pragma unroll
                for (int m = 0; m < 8; ++m)
                    rv[m] = atomicAdd(&sm.p.bcnt[bv[m]], 1);
            } else {
#pragma unroll
                for (int m = 0; m < 8; ++m) {
                    bool v = (off + m) < blen;
                    int e = base + off + m;
                    if (v) {
                        int d = __builtin_nontemporal_load(dst + e);
                        int s = __builtin_nontemporal_load(src + e);
                        float w = __builtin_nontemporal_load(ew + e);
                        sv[m] = s | ((d & (NPB - 1)) << 17);
                        wv[m] = w;
                        bv[m] = d >> BSH;
                        rv[m] = atomicAdd(&sm.p.bcnt[bv[m]], 1);
                    } else {
                        bv[m] = -1;
                    }
                }
            }
            __syncthreads();

            // exclusive scan of bcnt over 256 bins
            if (tid < MAXB1) sm.p.scan_[tid] = sm.p.bcnt[tid];
            __syncthreads();
            for (int o = 1; o < MAXB1; o <<= 1) {
                int t = 0;
                if (tid < MAXB1 && tid >= o) t = sm.p.scan_[tid - o];
                __syncthreads();
                if (tid < MAXB1) sm.p.scan_[tid] += t;
                __syncthreads();
            }
            if (tid < MAXB1) {
                sm.p.lbase[tid] = sm.p.scan_[tid] - sm.p.bcnt[tid];
                if (sm.p.bcnt[tid] > 0)
                    sm.p.bbase[tid] = atomicAdd(&cur1[tid * C1S], sm.p.bcnt[tid]);
            }
            __syncthreads();

            // stage: write pairs bin-sorted into LDS
#pragma unroll
            for (int m = 0; m < 8; ++m) {
                if (bv[m] >= 0) {
                    int slot = sm.p.lbase[bv[m]] + rv[m];
                    sm.p.tile[slot] = make_int2(sv[m], __float_as_int(wv[m]));
                    sm.p.binof[slot] = (unsigned char)bv[m];
                }
            }
            __syncthreads();

            // copy out: consecutive slots in a bin -> consecutive global addrs
            for (int i = tid; i < blen; i += 512) {
                int2 p = sm.p.tile[i];
                int bin = sm.p.binof[i];
                pairs1[sm.p.bbase[bin] + (i - sm.p.lbase[bin])] = p;
            }
            __syncthreads();
        }
    } else {
        // ---------- gemm body: h = x @ W -> bf16, 64 rows/block ----------
        int gidx = (int)pid - c;
        int j = tid & 63;
        int g = tid >> 6;                        // 0..7
        int base = gidx * 64;
        for (int i = tid; i < D * D; i += 512) sm.g.Ws[i] = W[i];
        for (int rr = g; rr < 64; rr += 8) {
            int r = base + rr;
            if (r < N) sm.g.xs[rr][j] = x[(size_t)r * D + j];
        }
        __syncthreads();
        float wc[D];
#pragma unroll
        for (int k = 0; k < D; ++k) wc[k] = sm.g.Ws[k * D + j];
        for (int rr = g; rr < 64; rr += 8) {
            int r = base + rr;
            if (r < N) {
                float s0 = 0.0f, s1 = 0.0f, s2 = 0.0f, s3 = 0.0f;
#pragma unroll
                for (int k = 0; k < D; k += 4) {
                    s0 = fmaf(sm.g.xs[rr][k + 0], wc[k + 0], s0);
                    s1 = fmaf(sm.g.xs[rr][k + 1], wc[k + 1], s1);
                    s2 = fmaf(sm.g.xs[rr][k + 2], wc[k + 2], s2);
                    s3 = fmaf(sm.g.xs[rr][k + 3], wc[k + 3], s3);
                }
                hbf[(size_t)r * D + j] = f2bf((s0 + s1) + (s2 + s3));
            }
        }
    }
}

// ---------------- 4. per-bucket exact counting sort -> compact cw ----------------
// One block (512 thr) per bucket. cw = { src:17 | wq:15 }.

__global__ __launch_bounds__(512) void sortmerge_kernel(const int2* __restrict__ pairs1,
                                                        const int* __restrict__ off1,
                                                        unsigned* __restrict__ cw,
                                                        int* __restrict__ node_off,
                                                        int N, int B1) {
    __shared__ int lh[NPB];
    __shared__ int s[NPB];
    __shared__ int cur[NPB];
    int tid = threadIdx.x;
    int c = blockIdx.x;
    int e0 = off1[c], e1 = off1[c + 1];

    lh[tid] = 0;
    __syncthreads();

    // pass 1: per-node histogram (unroll-8 staged loads)
    for (int ib = e0; ib < e1; ib += 512 * 8) {
        long long pv[8];
#pragma unroll
        for (int m = 0; m < 8; ++m) {
            int i = ib + m * 512 + tid;
            pv[m] = (i < e1)
                ? __builtin_nontemporal_load((const long long*)(pairs1 + i))
                : -1LL;
        }
#pragma unroll
        for (int m = 0; m < 8; ++m) {
            int i = ib + m * 512 + tid;
            if (i < e1) atomicAdd(&lh[((int)pv[m] >> 17) & (NPB - 1)], 1);
        }
    }
    __syncthreads();

    // scan 512 (Hillis-Steele, 512 threads)
    s[tid] = lh[tid];
    __syncthreads();
    for (int o = 1; o < NPB; o <<= 1) {
        int t = (tid >= o) ? s[tid - o] : 0;
        __syncthreads();
        s[tid] += t;
        __syncthreads();
    }
    int ex = s[tid] - lh[tid];
    int gbase = c << BSH;
    if (gbase + tid <= N) node_off[gbase + tid] = e0 + ex;
    if (c == B1 - 1 && tid == 0) node_off[N] = e1;
    cur[tid] = ex;
    __syncthreads();

    // pass 2: scatter into node-sorted compact stream
    for (int ib = e0; ib < e1; ib += 512 * 8) {
        long long pv[8];
#pragma unroll
        for (int m = 0; m < 8; ++m) {
            int i = ib + m * 512 + tid;
            pv[m] = (i < e1)
                ? __builtin_nontemporal_load((const long long*)(pairs1 + i))
                : -1LL;
        }
#pragma unroll
        for (int m = 0; m < 8; ++m) {
            int i = ib + m * 512 + tid;
            if (i < e1) {
                int px = (int)pv[m];
                float w = __int_as_float((int)(pv[m] >> 32));
                int node = (px >> 17) & (NPB - 1);
                int pos = atomicAdd(&cur[node], 1);
                int wq = (int)fminf(fmaxf(w, 0.0f) * WSCALE + 0.5f, 32767.0f);
                cw[e0 + pos] = (unsigned)(px & 0x1FFFF) | ((unsigned)wq << 17);
            }
        }
    }
}

// ---------------- 5. accumulate: wave-per-node, 4 edge-groups x uint2, unroll-4 ----------------

__global__ __launch_bounds__(256) void accum_kernel(const unsigned* __restrict__ cw,
                                                    const int* __restrict__ node_off,
                                                    const unsigned short* __restrict__ hbf,
                                                    const float* __restrict__ bias,
                                                    float* __restrict__ out, int N) {
    int t = blockIdx.x * 256 + threadIdx.x;
    int n = t >> 6;
    int l = t & 63;
    if (n >= N) return;
    int eg = l >> 4;          // edge subgroup 0..3: edges i ≡ eg (mod 4)
    int cl = l & 15;          // column group: cols [4cl, 4cl+4)
    int base = node_off[n];
    int cnt = node_off[n + 1] - base;
    const unsigned* pp = cw + base;
    const unsigned short* hcol = hbf + cl * 4;

    float a0 = 0.0f, a1 = 0.0f, a2 = 0.0f, a3 = 0.0f;
    float degs = 0.0f;
    int i = eg;
    // 4 edges per lane per iteration (16 wave-edges)
    for (; i + 12 < cnt; i += 16) {
        unsigned va = pp[i];
        unsigned vb = pp[i + 4];
        unsigned vc = pp[i + 8];
        unsigned vd = pp[i + 12];
        uint2 ha = *(const uint2*)(hcol + (size_t)(va & 0x1FFFF) * D);
        uint2 hb = *(const uint2*)(hcol + (size_t)(vb & 0x1FFFF) * D);
        uint2 hc = *(const uint2*)(hcol + (size_t)(vc & 0x1FFFF) * D);
        uint2 hd = *(const uint2*)(hcol + (size_t)(vd & 0x1FFFF) * D);
        float wa = (float)(va >> 17) * WINV;
        float wb = (float)(vb >> 17) * WINV;
        float wc = (float)(vc >> 17) * WINV;
        float wd = (float)(vd >> 17) * WINV;
        degs += (wa + wb) + (wc + wd);
        a0 = fmaf(wa, bflo(ha.x), a0);
        a1 = fmaf(wa, bfhi(ha.x), a1);
        a2 = fmaf(wa, bflo(ha.y), a2);
        a3 = fmaf(wa, bfhi(ha.y), a3);
        a0 = fmaf(wb, bflo(hb.x), a0);
        a1 = fmaf(wb, bfhi(hb.x), a1);
        a2 = fmaf(wb, bflo(hb.y), a2);
        a3 = fmaf(wb, bfhi(hb.y), a3);
        a0 = fmaf(wc, bflo(hc.x), a0);
        a1 = fmaf(wc, bfhi(hc.x), a1);
        a2 = fmaf(wc, bflo(hc.y), a2);
        a3 = fmaf(wc, bfhi(hc.y), a3);
        a0 = fmaf(wd, bflo(hd.x), a0);
        a1 = fmaf(wd, bfhi(hd.x), a1);
        a2 = fmaf(wd, bflo(hd.y), a2);
        a3 = fmaf(wd, bfhi(hd.y), a3);
    }
    for (; i < cnt; i += 4) {
        unsigned v = pp[i];
        uint2 hv = *(const uint2*)(hcol + (size_t)(v & 0x1FFFF) * D);
        float w = (float)(v >> 17) * WINV;
        degs += w;
        a0 = fmaf(w, bflo(hv.x), a0);
        a1 = fmaf(w, bfhi(hv.x), a1);
        a2 = fmaf(w, bflo(hv.y), a2);
        a3 = fmaf(w, bfhi(hv.y), a3);
    }

    // reduce the 4 edge groups (lanes differing in bits 4,5)
    a0 += __shfl_xor(a0, 16); a0 += __shfl_xor(a0, 32);
    a1 += __shfl_xor(a1, 16); a1 += __shfl_xor(a1, 32);
    a2 += __shfl_xor(a2, 16); a2 += __shfl_xor(a2, 32);
    a3 += __shfl_xor(a3, 16); a3 += __shfl_xor(a3, 32);
    degs += __shfl_xor(degs, 16); degs += __shfl_xor(degs, 32);

    if (eg == 0) {
        // self loop (weight 1)
        uint2 hs = *(const uint2*)(hcol + (size_t)n * D);
        a0 += bflo(hs.x);
        a1 += bfhi(hs.x);
        a2 += bflo(hs.y);
        a3 += bfhi(hs.y);
        degs += 1.0f;
        float di = 1.0f / degs;   // degs >= 1 (ew >= 0)
        const float4 bv = *(const float4*)(bias + cl * 4);
        float4 o;
        o.x = fmaf(di, a0, bv.x);
        o.y = fmaf(di, a1, bv.y);
        o.z = fmaf(di, a2, bv.z);
        o.w = fmaf(di, a3, bv.w);
        __builtin_nontemporal_store(o.x, out + (size_t)n * D + cl * 4 + 0);
        __builtin_nontemporal_store(o.y, out + (size_t)n * D + cl * 4 + 1);
        __builtin_nontemporal_store(o.z, out + (size_t)n * D + cl * 4 + 2);
        __builtin_nontemporal_store(o.w, out + (size_t)n * D + cl * 4 + 3);
    }
}

// ---------------- fallback (atomic path) ----------------

__global__ __launch_bounds__(256) void deg_kernel(const int* __restrict__ dst,
                                                  const float* __restrict__ ew,
                                                  float* __restrict__ deg, int E) {
    int t = blockIdx.x * 256 + threadIdx.x;
    int stride = gridDim.x * 256;
    for (int e = t; e < E; e += stride) atomicAdd(&deg[dst[e]], ew[e]);
}

__global__ __launch_bounds__(256) void deginv_kernel(float* __restrict__ deg, int N) {
    int t = blockIdx.x * 256 + threadIdx.x;
    int stride = gridDim.x * 256;
    for (int n = t; n < N; n += stride) {
        float tot = deg[n] + 1.0f;
        deg[n] = (tot > 0.0f) ? (1.0f / tot) : 0.0f;
    }
}

__global__ __launch_bounds__(256) void gemm16f_kernel(const float* __restrict__ x,
                                                      const float* __restrict__ W,
                                                      float* __restrict__ h, int N) {
    __shared__ float Ws[D * D];
    __shared__ float xs[16][D];
    int tid = threadIdx.x;
    int j = tid & 63;
    int q = tid >> 6;
    int base = blockIdx.x * 16;
    for (int i = tid; i < D * D; i += 256) Ws[i] = W[i];
    for (int rr = q; rr < 16; rr += 4) {
        int r = base + rr;
        if (r < N) xs[rr][j] = x[(size_t)r * D + j];
    }
    __syncthreads();
    for (int rr = q; rr < 16; rr += 4) {
        int r = base + rr;
        if (r < N) {
            float sum = 0.0f;
#pragma unroll
            for (int k = 0; k < D; ++k) sum = fmaf(xs[rr][k], Ws[k * D + j], sum);
            h[(size_t)r * D + j] = sum;
        }
    }
}

__global__ __launch_bounds__(256) void init_kernel(const float* __restrict__ h,
                                                   const float* __restrict__ deginv,
                                                   const float* __restrict__ b,
                                                   float* __restrict__ out, int N) {
    int t = blockIdx.x * 256 + threadIdx.x;
    int stride = gridDim.x * 256;
    int nq = N * (D / 4);
    const float4* h4 = (const float4*)h;
    const float4* b4 = (const float4*)b;
    float4* o4 = (float4*)out;
    for (int q = t; q < nq; q += stride) {
        int n = q >> 4;
        int c4 = q & 15;
        float4 hv = h4[q];
        float4 bv = b4[c4];
        float di = deginv[n];
        float4 o;
        o.x = bv.x + di * hv.x;
        o.y = bv.y + di * hv.y;
        o.z = bv.z + di * hv.z;
        o.w = bv.w + di * hv.w;
        o4[q] = o;
    }
}

__global__ __launch_bounds__(256) void scatter_kernel(const int* __restrict__ src,
                                                      const int* __restrict__ dst,
                                                      const float* __restrict__ ew,
                                                      const float* __restrict__ deginv,
                                                      const float* __restrict__ h,
                                                      float* __restrict__ out, int E) {
    int t = blockIdx.x * 256 + threadIdx.x;
    int wave = t >> 6;
    int lane = t & 63;
    int nwaves = (gridDim.x * 256) >> 6;
    for (int e = wave; e < E; e += nwaves) {
        int s = src[e];
        int d = dst[e];
        float norm = deginv[d] * ew[e];
        atomicAdd(&out[d * D + lane], norm * h[s * D + lane]);
    }
}

// ---------------- launcher ----------------

extern "C" void kernel_launch(void* const* d_in, const int* in_sizes, int n_in,
                              void* d_out, int out_size, void* d_ws, size_t ws_size,
                              hipStream_t stream) {
    const float* x  = (const float*)d_in[0];
    const int*   ei = (const int*)d_in[1];
    const float* ew = (const float*)d_in[2];
    const float* W  = (const float*)d_in[3];
    const float* b  = (const float*)d_in[4];
    float* out = (float*)d_out;

    int N = in_sizes[0] / D;
    int E = in_sizes[2];
    const int* srcp = ei;
    const int* dstp = ei + E;

    int B1 = (N + NPB - 1) >> BSH;

    // ws ints: hist[256] | off1[320] | cur1[256*C1S] | node_off[N+64]
    // then pairs1 (E*8), hbf (N*D*2), cw (E*4)
    size_t ints_n = 256 + 320 + (size_t)MAXB1 * C1S + ((size_t)N + 64);
    size_t p1_off  = ((ints_n * 4) + 255) & ~(size_t)255;
    size_t hbf_off = (p1_off + (size_t)E * 8 + 255) & ~(size_t)255;
    size_t cw_off  = (hbf_off + (size_t)N * D * 2 + 255) & ~(size_t)255;
    size_t need = cw_off + (size_t)E * 4;

    if (N <= 131072 && ws_size >= need) {
        int* hist     = (int*)d_ws;
        int* off1     = hist + 256;
        int* cur1     = off1 + 320;
        int* node_off = cur1 + (size_t)MAXB1 * C1S;
        int2* pairs1  = (int2*)((char*)d_ws + p1_off);
        unsigned short* hbf = (unsigned short*)((char*)d_ws + hbf_off);
        unsigned* cw  = (unsigned*)((char*)d_ws + cw_off);

        int aligned = (((E & 3) == 0) && (((size_t)dstp & 15) == 0)) ? 1 : 0;

        hipMemsetAsync(hist, 0, 256 * 4, stream);
        hist_kernel<<<512, 256, 0, stream>>>(dstp, hist, E, B1);
        scan_kernel<<<1, 256, 0, stream>>>(hist, off1, cur1, B1, E);
        int nb = (E + BATCHA - 1) / BATCHA;
        int gA = nb < 2048 ? nb : 2048;
        int gG = (N + 63) / 64;
        int total = gA + gG;
        partgemm_kernel<<<total, 512, 0, stream>>>(srcp, dstp, ew, cur1, pairs1,
                                                   E, nb, aligned, gA, total,
                                                   x, W, hbf, N);
        sortmerge_kernel<<<B1, 512, 0, stream>>>(pairs1, off1, cw, node_off, N, B1);
        accum_kernel<<<(N + 3) / 4, 256, 0, stream>>>(cw, node_off, hbf, b, out, N);
    } else {
        // fallback: atomic scatter path
        size_t Npad = ((size_t)N + 63) & ~(size_t)63;
        float* deg = (float*)d_ws;
        float* h = deg + Npad;
        hipMemsetAsync(deg, 0, (size_t)N * sizeof(float), stream);
        deg_kernel<<<2048, 256, 0, stream>>>(dstp, ew, deg, E);
        deginv_kernel<<<(N + 255) / 256, 256, 0, stream>>>(deg, N);
        gemm16f_kernel<<<(N + 15) / 16, 256, 0, stream>>>(x, W, h, N);
        init_kernel<<<2048, 256, 0, stream>>>(h, deg, b, out, N);
        scatter_kernel<<<2048, 256, 0, stream>>>(srcp, dstp, ew, deg, h, out, E);
    }
}